// Round 6
// baseline (9416.842 us; speedup 1.0000x reference)
//
#include <hip/hip_runtime.h>

#define HH   100
#define LL   4096
#define NT   1024
#define NLDSROW 176      // rows 0..175 (Whh0 gates 0..175) streamed from LDS
#define RB0  176         // first register-resident row
// Row space r in [0,1200): [0,400) Whh0 (src h1), [400,800) Wih1 (src h1), [800,1200) Whh1 (src h2).
// Thread layout: half = tid>>9 (cols [50*half,50*half+50)), gtid = tid&511, rows {176+2*gtid, 177+2*gtid}.
// h broadcast: per-wave ds_read_b32 stage + 50 readlanes -> 50 SGPRs. Straddle waves 4,12 use VGPR-h.

// LDS floats: x[4096] wq[2*176*52] part[2*1204] h1[100] h2[100] red[100]
#define WQ_OFF   4096
#define PART_OFF (WQ_OFF + 2*NLDSROW*52)      // 22400
#define H1_OFF   (PART_OFF + 2*1204)          // 24808
#define H2_OFF   (H1_OFF + HH)                // 24908
#define RED_OFF  (H2_OFF + HH)                // 25008
#define LDS_FLOATS (RED_OFF + HH)             // 25108

__device__ __forceinline__ float sigmoidf_(float x) {
    return 1.0f / (1.0f + __expf(-x));
}
__device__ __forceinline__ float tanhf_(float x) {
    return 1.0f - 2.0f / (__expf(2.0f * x) + 1.0f);
}

// ---- named register rows: 12 float4 + 1 float2 = 50 floats ----
#define DECLROW(n) float4 n##_0,n##_1,n##_2,n##_3,n##_4,n##_5,n##_6,n##_7,n##_8,n##_9,n##_10,n##_11; float2 n##_12;
#define PAIR4(n,i,q2) n##_##i = make_float4((q2)[2*(i)].x,(q2)[2*(i)].y,(q2)[2*(i)+1].x,(q2)[2*(i)+1].y);
#define LOADROW(n, P) { const float2* q2_ = reinterpret_cast<const float2*>(P); \
  PAIR4(n,0,q2_) PAIR4(n,1,q2_) PAIR4(n,2,q2_) PAIR4(n,3,q2_) PAIR4(n,4,q2_) PAIR4(n,5,q2_) \
  PAIR4(n,6,q2_) PAIR4(n,7,q2_) PAIR4(n,8,q2_) PAIR4(n,9,q2_) PAIR4(n,10,q2_) PAIR4(n,11,q2_) \
  n##_12 = q2_[24]; }

// ---- readlane h -> named scalars (uniform => SGPR) ----
#define RL(k) const float s##k = __uint_as_float(__builtin_amdgcn_readlane(hvu, k));

// ---- dot: two register rows against 4 scalars ----
#define DOT4(i,A,B,C,D) \
  a0=fmaf(wa_##i.x,A,a0); a0=fmaf(wa_##i.y,B,a0); a0=fmaf(wa_##i.z,C,a0); a0=fmaf(wa_##i.w,D,a0); \
  a1=fmaf(wb_##i.x,A,a1); a1=fmaf(wb_##i.y,B,a1); a1=fmaf(wb_##i.z,C,a1); a1=fmaf(wb_##i.w,D,a1);

// ---- LDS-streamed task row against 4 scalars ----
#define TSK4(j,A,B,C,D) { float4 wv=wp4[j]; tq=fmaf(wv.x,A,tq); tq=fmaf(wv.y,B,tq); \
                          tq=fmaf(wv.z,C,tq); tq=fmaf(wv.w,D,tq); }

// ---- straddle-wave dot: per-lane h from LDS (float2 pairs) ----
#define SD4(i) { float2 h01=hp2[2*(i)], h23=hp2[2*(i)+1]; \
  a0=fmaf(wa_##i.x,h01.x,a0); a0=fmaf(wa_##i.y,h01.y,a0); a0=fmaf(wa_##i.z,h23.x,a0); a0=fmaf(wa_##i.w,h23.y,a0); \
  a1=fmaf(wb_##i.x,h01.x,a1); a1=fmaf(wb_##i.y,h01.y,a1); a1=fmaf(wb_##i.z,h23.x,a1); a1=fmaf(wb_##i.w,h23.y,a1); }

__global__ __launch_bounds__(NT)
void lstm_sgpr_kernel(const float* __restrict__ x_seq,
                      const float* __restrict__ Wih0,
                      const float* __restrict__ Whh0,
                      const float* __restrict__ bih0,
                      const float* __restrict__ bhh0,
                      const float* __restrict__ Wih1,
                      const float* __restrict__ Whh1,
                      const float* __restrict__ bih1,
                      const float* __restrict__ bhh1,
                      const float* __restrict__ Wlin,
                      const float* __restrict__ blin,
                      float* __restrict__ out)
{
    extern __shared__ float lds[];
    float* x_s   = lds;
    float* wq    = lds + WQ_OFF;     // [2][176][52]
    float* part  = lds + PART_OFF;   // [2][1204]
    float* h1_s  = lds + H1_OFF;     // [100]
    float* h2_s  = lds + H2_OFF;     // [100]
    float* red   = lds + RED_OFF;    // [100]

    const int tid  = threadIdx.x;
    const int lane = tid & 63;
    const int wid  = tid >> 6;
    const int half = tid >> 9;           // 0 or 1
    const int gtid = tid & 511;          // 0..511
    const int r0   = RB0 + 2*gtid;       // even; r0,r0+1 same region
    const bool straddle = (wid == 4) || (wid == 12);

    // ---- prologue ----
    {
        const float4* src = reinterpret_cast<const float4*>(x_seq);
        float4*       dst = reinterpret_cast<float4*>(x_s);
        for (int i = tid; i < LL/4; i += NT) dst[i] = src[i];
    }
    for (int idx = tid; idx < 2*NLDSROW*50; idx += NT) {
        int hf  = idx / (NLDSROW*50);
        int rem = idx - hf*(NLDSROW*50);
        int row = rem / 50;
        int c   = rem - row*50;
        wq[(hf*NLDSROW + row)*52 + c] = Whh0[row*HH + hf*50 + c];
    }
    if (tid < HH) { h1_s[tid] = 0.0f; h2_s[tid] = 0.0f; }

    // region-select row pointers
    const float* P0;
    const float* P1;
    {
        int r1 = r0 + 1;
        P0 = (r0 < 400) ? (Whh0 + r0*HH) : (r0 < 800) ? (Wih1 + (r0-400)*HH) : (Whh1 + (r0-800)*HH);
        P1 = (r1 < 400) ? (Whh0 + r1*HH) : (r1 < 800) ? (Wih1 + (r1-400)*HH) : (Whh1 + (r1-800)*HH);
    }
    DECLROW(wa) DECLROW(wb)
    LOADROW(wa, P0 + half*50)
    LOADROW(wb, P1 + half*50)

    // bias/wx (applied by half 0 only)
    float bw0 = 0.f, bw1 = 0.f, wx0 = 0.f, wx1 = 0.f;
    if (half == 0) {
        int r1 = r0 + 1;
        bw0 = (r0 < 400) ? (bih0[r0] + bhh0[r0]) : (r0 < 800) ? (bih1[r0-400] + bhh1[r0-400]) : 0.0f;
        bw1 = (r1 < 400) ? (bih0[r1] + bhh0[r1]) : (r1 < 800) ? (bih1[r1-400] + bhh1[r1-400]) : 0.0f;
        wx0 = (r0 < 400) ? Wih0[r0] : 0.0f;
        wx1 = (r1 < 400) ? Wih0[r1] : 0.0f;
    }

    // LDS-task constants (rows 0..175, this thread's half)
    float tbe = 0.f, twxe = 0.f;
    if (gtid < NLDSROW && half == 0) {
        tbe  = bih0[gtid] + bhh0[gtid];
        twxe = Wih0[gtid];
    }

    // h staging base for pure waves (wave-uniform source)
    const float* hbase = ((gtid < 312) ? h1_s : h2_s) + half*50;
    const int   sidx   = (lane < 50) ? lane : 49;

    // straddle-wave per-lane h pointer
    const float2* hp2 = reinterpret_cast<const float2*>(((gtid < 312) ? h1_s : h2_s) + half*50);

    float* pbase = part + half*1204;
    const float wl = (tid < HH) ? Wlin[tid] : 0.0f;
    float c0 = 0.0f, c1 = 0.0f;

    __syncthreads();

    for (int t = 0; t <= LL; ++t) {
        const float xt = x_s[(t < LL) ? t : (LL-1)];

        // ================= phase 1: dots =================
        if (straddle) {
            float a0 = 0.f, a1 = 0.f;
            SD4(0) SD4(1) SD4(2) SD4(3) SD4(4) SD4(5)
            SD4(6) SD4(7) SD4(8) SD4(9) SD4(10) SD4(11)
            { float2 h01 = hp2[24];
              a0 = fmaf(wa_12.x,h01.x,a0); a0 = fmaf(wa_12.y,h01.y,a0);
              a1 = fmaf(wb_12.x,h01.x,a1); a1 = fmaf(wb_12.y,h01.y,a1); }
            float p0v = fmaf(wx0, xt, a0 + bw0);
            float p1v = fmaf(wx1, xt, a1 + bw1);
            reinterpret_cast<float2*>(pbase + RB0)[gtid] = make_float2(p0v, p1v);
        } else {
            // stage h into SGPRs: one lane-indexed read + 50 readlanes
            const float hv = hbase[sidx];
            const unsigned hvu = __float_as_uint(hv);
            RL(0) RL(1) RL(2) RL(3) RL(4) RL(5) RL(6) RL(7) RL(8) RL(9)
            RL(10) RL(11) RL(12) RL(13) RL(14) RL(15) RL(16) RL(17) RL(18) RL(19)
            RL(20) RL(21) RL(22) RL(23) RL(24) RL(25) RL(26) RL(27) RL(28) RL(29)
            RL(30) RL(31) RL(32) RL(33) RL(34) RL(35) RL(36) RL(37) RL(38) RL(39)
            RL(40) RL(41) RL(42) RL(43) RL(44) RL(45) RL(46) RL(47) RL(48) RL(49)

            float a0 = 0.f, a1 = 0.f;
            DOT4(0, s0,s1,s2,s3)    DOT4(1, s4,s5,s6,s7)    DOT4(2, s8,s9,s10,s11)
            DOT4(3, s12,s13,s14,s15)  DOT4(4, s16,s17,s18,s19)  DOT4(5, s20,s21,s22,s23)
            DOT4(6, s24,s25,s26,s27)  DOT4(7, s28,s29,s30,s31)  DOT4(8, s32,s33,s34,s35)
            DOT4(9, s36,s37,s38,s39)  DOT4(10, s40,s41,s42,s43) DOT4(11, s44,s45,s46,s47)
            a0 = fmaf(wa_12.x, s48, a0); a0 = fmaf(wa_12.y, s49, a0);
            a1 = fmaf(wb_12.x, s48, a1); a1 = fmaf(wb_12.y, s49, a1);

            float p0v = fmaf(wx0, xt, a0 + bw0);
            float p1v = fmaf(wx1, xt, a1 + bw1);
            reinterpret_cast<float2*>(pbase + RB0)[gtid] = make_float2(p0v, p1v);

            // LDS-streamed rows 0..175 (h1-source; these waves are pure-h1)
            if (gtid < NLDSROW) {
                const float4* wp4 = reinterpret_cast<const float4*>(wq + (half*NLDSROW + gtid)*52);
                float tq = 0.f;
                TSK4(0, s0,s1,s2,s3)    TSK4(1, s4,s5,s6,s7)    TSK4(2, s8,s9,s10,s11)
                TSK4(3, s12,s13,s14,s15)  TSK4(4, s16,s17,s18,s19)  TSK4(5, s20,s21,s22,s23)
                TSK4(6, s24,s25,s26,s27)  TSK4(7, s28,s29,s30,s31)  TSK4(8, s32,s33,s34,s35)
                TSK4(9, s36,s37,s38,s39)  TSK4(10, s40,s41,s42,s43) TSK4(11, s44,s45,s46,s47)
                { const float2 wv = reinterpret_cast<const float2*>(wq + (half*NLDSROW + gtid)*52)[24];
                  tq = fmaf(wv.x, s48, tq); tq = fmaf(wv.y, s49, tq); }
                pbase[gtid] = fmaf(twxe, xt, tq + tbe);
            }
        }
        __syncthreads();

        // ================= phase 2: gating =================
        if (tid >= 384 && tid < 384 + HH) {              // L0 gating -> h1(t)
            if (t < LL) {
                const int j = tid - 384;
                float g0 = part[j]       + part[1204 + j];
                float g1 = part[j + 100] + part[1204 + j + 100];
                float g2 = part[j + 200] + part[1204 + j + 200];
                float g3 = part[j + 300] + part[1204 + j + 300];
                c0 = sigmoidf_(g1)*c0 + sigmoidf_(g0)*tanhf_(g2);
                h1_s[j] = sigmoidf_(g3)*tanhf_(c0);
            }
        } else if (tid >= 896 && tid < 896 + HH) {       // L1 gating -> h2(t-1)
            if (t >= 1) {
                const int j = tid - 896;
                float v0 = (part[400+j]  + part[1204+400+j])  + (part[800+j]  + part[1204+800+j]);
                float v1 = (part[500+j]  + part[1204+500+j])  + (part[900+j]  + part[1204+900+j]);
                float v2 = (part[600+j]  + part[1204+600+j])  + (part[1000+j] + part[1204+1000+j]);
                float v3 = (part[700+j]  + part[1204+700+j])  + (part[1100+j] + part[1204+1100+j]);
                c1 = sigmoidf_(v1)*c1 + sigmoidf_(v0)*tanhf_(v2);
                h2_s[j] = sigmoidf_(v3)*tanhf_(c1);
            }
        }
        __syncthreads();
    }

    // ---- final projection ----
    if (tid < HH) red[tid] = wl * h2_s[tid];
    __syncthreads();
    if (tid == 0) {
        float s = blin[0];
        for (int k = 0; k < HH; ++k) s += red[k];
        out[0] = s;
    }
}

extern "C" void kernel_launch(void* const* d_in, const int* in_sizes, int n_in,
                              void* d_out, int out_size, void* d_ws, size_t ws_size,
                              hipStream_t stream) {
    (void)in_sizes; (void)n_in; (void)out_size; (void)d_ws; (void)ws_size;

    const float* x_seq = (const float*)d_in[0];
    const float* Wih0  = (const float*)d_in[1];
    const float* Whh0  = (const float*)d_in[2];
    const float* bih0  = (const float*)d_in[3];
    const float* bhh0  = (const float*)d_in[4];
    const float* Wih1  = (const float*)d_in[5];
    const float* Whh1  = (const float*)d_in[6];
    const float* bih1  = (const float*)d_in[7];
    const float* bhh1  = (const float*)d_in[8];
    const float* Wlin  = (const float*)d_in[9];
    const float* blin  = (const float*)d_in[10];
    float* out = (float*)d_out;

    static bool attr_set = false;
    if (!attr_set) {
        hipFuncSetAttribute((const void*)lstm_sgpr_kernel,
                            hipFuncAttributeMaxDynamicSharedMemorySize,
                            LDS_FLOATS * (int)sizeof(float));
        attr_set = true;
    }

    hipLaunchKernelGGL(lstm_sgpr_kernel, dim3(1), dim3(NT),
                       LDS_FLOATS * sizeof(float), stream,
                       x_seq, Wih0, Whh0, bih0, bhh0,
                       Wih1, Whh1, bih1, bhh1, Wlin, blin, out);
}

// Round 7
// 9009.544 us; speedup vs baseline: 1.0452x; 1.0452x over previous
//
#include <hip/hip_runtime.h>

#define HH 100
#define LL 4096
#define NT 1024
#define NTASK1 160           // LDS rows: Whh0 gate-rows 0..159  (h1 source)
#define NTASK2 16            // LDS rows: Whh1 gate-rows 0..15   (h2 source, global rows 800..815)
#define NTASKS (NTASK1 + NTASK2)
// Row space r in [0,1200): [0,400) Whh0 (h1), [400,800) Wih1 (h1), [800,1200) Whh1 (h2).
// Register rows: 160..799 (g in [0,320)) and 816..1199 (g in [320,512)); thread = 2 rows x 1 col-half.
// Waves (per half): 0..4 pure-h1, 5..7 pure-h2 -> no straddle; gating done lane-parallel in every wave.

// LDS floats: x[4096] wq[2][176][52] part[2buf][2hf][1204] red[128]
#define WQ_OFF   4096
#define PART_OFF (WQ_OFF + 2*NTASKS*52)      // 22400
#define RED_OFF  (PART_OFF + 2*2*1204)       // 27216
#define LDS_FLOATS (RED_OFF + 128)           // 27344 floats = 109.4 KB

__device__ __forceinline__ float sigmoidf_(float x) {
    return 1.0f / (1.0f + __expf(-x));
}
__device__ __forceinline__ float tanhf_(float x) {
    return 1.0f - 2.0f / (__expf(2.0f * x) + 1.0f);
}

// ---- named register rows: 12 float4 + 1 float2 = 50 floats (no alloca -> no scratch/AGPR array) ----
#define DECLROW(n) float4 n##_0,n##_1,n##_2,n##_3,n##_4,n##_5,n##_6,n##_7,n##_8,n##_9,n##_10,n##_11; float2 n##_12;
#define PAIR4(n,i,q2) n##_##i = make_float4((q2)[2*(i)].x,(q2)[2*(i)].y,(q2)[2*(i)+1].x,(q2)[2*(i)+1].y);
#define LOADROW(n, P) { const float2* q2_ = reinterpret_cast<const float2*>(P); \
  PAIR4(n,0,q2_) PAIR4(n,1,q2_) PAIR4(n,2,q2_) PAIR4(n,3,q2_) PAIR4(n,4,q2_) PAIR4(n,5,q2_) \
  PAIR4(n,6,q2_) PAIR4(n,7,q2_) PAIR4(n,8,q2_) PAIR4(n,9,q2_) PAIR4(n,10,q2_) PAIR4(n,11,q2_) \
  n##_12 = q2_[24]; }

// ---- readlane h -> named scalars (wave-uniform => SGPR) ----
#define RL(k) const float s##k = __uint_as_float(__builtin_amdgcn_readlane(hvu, k));

// ---- dot: two register rows against 4 broadcast scalars ----
#define DOT4(i,A,B,C,D) \
  a0=fmaf(wa_##i.x,A,a0); a0=fmaf(wa_##i.y,B,a0); a0=fmaf(wa_##i.z,C,a0); a0=fmaf(wa_##i.w,D,a0); \
  a1=fmaf(wb_##i.x,A,a1); a1=fmaf(wb_##i.y,B,a1); a1=fmaf(wb_##i.z,C,a1); a1=fmaf(wb_##i.w,D,a1);

// ---- LDS-streamed task row against 4 broadcast scalars ----
#define TSK4(j,A,B,C,D) { float4 wv4=twp4[j]; tq=fmaf(wv4.x,A,tq); tq=fmaf(wv4.y,B,tq); \
                          tq=fmaf(wv4.z,C,tq); tq=fmaf(wv4.w,D,tq); }

__global__ __launch_bounds__(NT, 1)
void lstm_1bar_kernel(const float* __restrict__ x_seq,
                      const float* __restrict__ Wih0,
                      const float* __restrict__ Whh0,
                      const float* __restrict__ bih0,
                      const float* __restrict__ bhh0,
                      const float* __restrict__ Wih1,
                      const float* __restrict__ Whh1,
                      const float* __restrict__ bih1,
                      const float* __restrict__ bhh1,
                      const float* __restrict__ Wlin,
                      const float* __restrict__ blin,
                      float* __restrict__ out)
{
    extern __shared__ float lds[];
    float* x_s  = lds;
    float* wq   = lds + WQ_OFF;      // [2][176][52]
    float* part = lds + PART_OFF;    // [2 buf][2 hf][1204]
    float* red  = lds + RED_OFF;     // [128]

    const int tid  = threadIdx.x;
    const int lane = tid & 63;
    const int hf   = tid >> 9;           // column half: 0 or 1
    const int g    = tid & 511;          // 0..511
    const int wvh  = g >> 6;             // wave-in-half: 0..7
    const bool is_h1 = (g < 320);        // waves 0..4 h1-source, 5..7 h2-source

    // ---- prologue: x (coalesced) ----
    {
        const float4* src = reinterpret_cast<const float4*>(x_seq);
        float4*       dst = reinterpret_cast<float4*>(x_s);
        for (int i = tid; i < LL/4; i += NT) dst[i] = src[i];
    }
    // ---- wq staging: [hf][slot][52]; slot<160 -> Whh0 row slot; else Whh1 row slot-160 ----
    for (int idx = tid; idx < 2*NTASKS*50; idx += NT) {
        int h   = idx / (NTASKS*50);
        int rem = idx - h*(NTASKS*50);
        int s   = rem / 50;
        int c   = rem - s*50;
        float v = (s < NTASK1) ? Whh0[s*HH + h*50 + c]
                               : Whh1[(s-NTASK1)*HH + h*50 + c];
        wq[(h*NTASKS + s)*52 + c] = v;
    }

    // ---- register rows ----
    int row0;
    const float* M;
    if (g < 120)      { row0 = 160 + 2*g;        M = Whh0 + row0*HH; }
    else if (g < 320) { row0 = 160 + 2*g;        M = Wih1 + (row0-400)*HH; }
    else              { row0 = 816 + 2*(g-320);  M = Whh1 + (row0-800)*HH; }
    DECLROW(wa) DECLROW(wb)
    LOADROW(wa, M + hf*50)
    LOADROW(wb, M + HH + hf*50)

    // bias (applied by half0) / wx (applied by half1, L0 rows only)
    float bw0, bw1;
    {
        const int r0 = row0, r1 = row0 + 1;
        if (hf == 0) {
            bw0 = (r0 < 400) ? (bih0[r0] + bhh0[r0]) : (r0 < 800) ? (bih1[r0-400] + bhh1[r0-400]) : 0.0f;
            bw1 = (r1 < 400) ? (bih0[r1] + bhh0[r1]) : (r1 < 800) ? (bih1[r1-400] + bhh1[r1-400]) : 0.0f;
        } else {
            bw0 = (r0 < 400) ? Wih0[r0] : 0.0f;
            bw1 = (r1 < 400) ? Wih0[r1] : 0.0f;
        }
    }

    // ---- LDS-task assignment (task thread's h-class matches task row's source) ----
    const bool has_task = is_h1 ? (g >= 160) : (g < 336);
    const int  tslot    = is_h1 ? (g - 160) : (NTASK1 + (g - 320));     // 0..175
    const int  trow     = (tslot < NTASK1) ? tslot : (800 + (tslot - NTASK1));
    const float4* twp4  = reinterpret_cast<const float4*>(wq + (hf*NTASKS + tslot)*52);
    float tbw = 0.0f;
    if (has_task && tslot < NTASK1) tbw = (hf == 0) ? (bih0[tslot] + bhh0[tslot]) : Wih0[tslot];

    // ---- epilogue weights (first h2 wave of each half) ----
    float wl = 0.0f;
    if (wvh == 5 && lane < 50) wl = Wlin[hf*50 + lane];

    const int elane = (lane < 50) ? lane : 49;   // gating element index within half
    const int e     = hf*50 + elane;

    float h_lane = 0.0f, c_lane = 0.0f;
    __syncthreads();

    for (int t = 0; t <= LL; ++t) {
        const float xt  = x_s[(t < LL) ? t : (LL-1)];
        const float xvs = hf ? xt : 1.0f;
        float*       pw  = part + (t & 1)*2408 + hf*1204;
        const float* pr0 = part + (t & 1)*2408;
        const float* pr1 = pr0 + 1204;

        // ---- stage own-class h into SGPRs (1 bitcast + 50 readlanes; no LDS) ----
        const unsigned hvu = __float_as_uint(h_lane);
        RL(0) RL(1) RL(2) RL(3) RL(4) RL(5) RL(6) RL(7) RL(8) RL(9)
        RL(10) RL(11) RL(12) RL(13) RL(14) RL(15) RL(16) RL(17) RL(18) RL(19)
        RL(20) RL(21) RL(22) RL(23) RL(24) RL(25) RL(26) RL(27) RL(28) RL(29)
        RL(30) RL(31) RL(32) RL(33) RL(34) RL(35) RL(36) RL(37) RL(38) RL(39)
        RL(40) RL(41) RL(42) RL(43) RL(44) RL(45) RL(46) RL(47) RL(48) RL(49)

        // ---- register-row dots ----
        float a0 = 0.f, a1 = 0.f;
        DOT4(0, s0,s1,s2,s3)      DOT4(1, s4,s5,s6,s7)      DOT4(2, s8,s9,s10,s11)
        DOT4(3, s12,s13,s14,s15)  DOT4(4, s16,s17,s18,s19)  DOT4(5, s20,s21,s22,s23)
        DOT4(6, s24,s25,s26,s27)  DOT4(7, s28,s29,s30,s31)  DOT4(8, s32,s33,s34,s35)
        DOT4(9, s36,s37,s38,s39)  DOT4(10, s40,s41,s42,s43) DOT4(11, s44,s45,s46,s47)
        a0 = fmaf(wa_12.x, s48, a0); a0 = fmaf(wa_12.y, s49, a0);
        a1 = fmaf(wb_12.x, s48, a1); a1 = fmaf(wb_12.y, s49, a1);
        a0 = fmaf(bw0, xvs, a0);
        a1 = fmaf(bw1, xvs, a1);
        *reinterpret_cast<float2*>(pw + row0) = make_float2(a0, a1);   // row0 even -> aligned b64

        // ---- LDS-streamed task row ----
        if (has_task) {
            float tq = 0.f;
            TSK4(0, s0,s1,s2,s3)      TSK4(1, s4,s5,s6,s7)      TSK4(2, s8,s9,s10,s11)
            TSK4(3, s12,s13,s14,s15)  TSK4(4, s16,s17,s18,s19)  TSK4(5, s20,s21,s22,s23)
            TSK4(6, s24,s25,s26,s27)  TSK4(7, s28,s29,s30,s31)  TSK4(8, s32,s33,s34,s35)
            TSK4(9, s36,s37,s38,s39)  TSK4(10, s40,s41,s42,s43) TSK4(11, s44,s45,s46,s47)
            { const float2 wv2 = reinterpret_cast<const float2*>(twp4)[24];
              tq = fmaf(wv2.x, s48, tq); tq = fmaf(wv2.y, s49, tq); }
            pw[trow] = fmaf(tbw, xvs, tq);
        }

        __syncthreads();   // the ONLY barrier per step

        // ---- lane-parallel gating (every wave computes its own 50 h elements) ----
        if (is_h1) {
            float G0 = pr0[e]     + pr1[e];
            float G1 = pr0[e+100] + pr1[e+100];
            float G2 = pr0[e+200] + pr1[e+200];
            float G3 = pr0[e+300] + pr1[e+300];
            c_lane = sigmoidf_(G1)*c_lane + sigmoidf_(G0)*tanhf_(G2);
            h_lane = sigmoidf_(G3)*tanhf_(c_lane);
        } else if (t >= 1) {
            float G0 = (pr0[400+e]     + pr1[400+e])     + (pr0[800+e]     + pr1[800+e]);
            float G1 = (pr0[500+e]     + pr1[500+e])     + (pr0[900+e]     + pr1[900+e]);
            float G2 = (pr0[600+e]     + pr1[600+e])     + (pr0[1000+e]    + pr1[1000+e]);
            float G3 = (pr0[700+e]     + pr1[700+e])     + (pr0[1100+e]    + pr1[1100+e]);
            c_lane = sigmoidf_(G1)*c_lane + sigmoidf_(G0)*tanhf_(G2);
            h_lane = sigmoidf_(G3)*tanhf_(c_lane);
        }
        // no second barrier: next iteration writes the other part buffer
    }

    // ---- final projection: h2(LL-1) lives in lanes<50 of wave wvh==5 of each half ----
    if (wvh == 5 && lane < 50) red[hf*50 + lane] = wl * h_lane;
    __syncthreads();
    if (tid == 0) {
        float s = blin[0];
        for (int k = 0; k < HH; ++k) s += red[k];
        out[0] = s;
    }
}

extern "C" void kernel_launch(void* const* d_in, const int* in_sizes, int n_in,
                              void* d_out, int out_size, void* d_ws, size_t ws_size,
                              hipStream_t stream) {
    (void)in_sizes; (void)n_in; (void)out_size; (void)d_ws; (void)ws_size;

    const float* x_seq = (const float*)d_in[0];
    const float* Wih0  = (const float*)d_in[1];
    const float* Whh0  = (const float*)d_in[2];
    const float* bih0  = (const float*)d_in[3];
    const float* bhh0  = (const float*)d_in[4];
    const float* Wih1  = (const float*)d_in[5];
    const float* Whh1  = (const float*)d_in[6];
    const float* bih1  = (const float*)d_in[7];
    const float* bhh1  = (const float*)d_in[8];
    const float* Wlin  = (const float*)d_in[9];
    const float* blin  = (const float*)d_in[10];
    float* out = (float*)d_out;

    static bool attr_set = false;
    if (!attr_set) {
        hipFuncSetAttribute((const void*)lstm_1bar_kernel,
                            hipFuncAttributeMaxDynamicSharedMemorySize,
                            LDS_FLOATS * (int)sizeof(float));
        attr_set = true;
    }

    hipLaunchKernelGGL(lstm_1bar_kernel, dim3(1), dim3(NT),
                       LDS_FLOATS * sizeof(float), stream,
                       x_seq, Wih0, Whh0, bih0, bhh0,
                       Wih1, Whh1, bih1, bhh1, Wlin, blin, out);
}

// Round 8
// 8458.776 us; speedup vs baseline: 1.1133x; 1.0651x over previous
//
#include <hip/hip_runtime.h>

#define HH 100
#define LL 4096
#define NT 512
#define NTASKS 176
// Row space r in [0,1200): [0,400) Whh0 (src h1), [400,800) Wih1 (src h1), [800,1200) Whh1 (src h2).
// Waves (wid 0..7): hf = wid&1 (col half), class = h1 for wid<6 else h2.
//   h1 threads: j = (wid>>1)*64+lane in [0,192), reg rows 32+4j .. 35+4j  (covers 32..799)
//   h2 threads: j2 = lane, reg rows 944+4*j2 .. 947+4*j2                  (covers 944..1199)
// LDS task rows: Whh0 rows 0..31 (hosted by h1 lanes j<32), Whh1 rows 0..143 (h2 lanes, 2-3 each).
// h broadcast: lane-parallel redundant gating keeps h in lane regs; 50 readlanes -> SGPRs. ONE barrier/step.

// LDS floats: x[4096] wq[2][176][52] part[2buf][2hf][1204] red[128]
#define WQ_OFF   4096
#define PART_OFF (WQ_OFF + 2*NTASKS*52)     // 22400
#define RED_OFF  (PART_OFF + 2*2*1204)      // 27216
#define LDS_FLOATS (RED_OFF + 128)          // 27344 floats = 109.4 KB

__device__ __forceinline__ float sigmoidf_(float x) {
    return 1.0f / (1.0f + __expf(-x));
}
__device__ __forceinline__ float tanhf_(float x) {
    return 1.0f - 2.0f / (__expf(2.0f * x) + 1.0f);
}

// ---- named register rows: 12 float4 + 1 float2 = 50 floats (no alloca) ----
#define DECLROW(n) float4 n##_0,n##_1,n##_2,n##_3,n##_4,n##_5,n##_6,n##_7,n##_8,n##_9,n##_10,n##_11; float2 n##_12;
#define PAIR4(n,i,q2) n##_##i = make_float4((q2)[2*(i)].x,(q2)[2*(i)].y,(q2)[2*(i)+1].x,(q2)[2*(i)+1].y);
#define LOADROW(n, P) { const float2* q2_ = reinterpret_cast<const float2*>(P); \
  PAIR4(n,0,q2_) PAIR4(n,1,q2_) PAIR4(n,2,q2_) PAIR4(n,3,q2_) PAIR4(n,4,q2_) PAIR4(n,5,q2_) \
  PAIR4(n,6,q2_) PAIR4(n,7,q2_) PAIR4(n,8,q2_) PAIR4(n,9,q2_) PAIR4(n,10,q2_) PAIR4(n,11,q2_) \
  n##_12 = q2_[24]; }

// ---- readlane h -> named scalars (wave-uniform => SGPR) ----
#define RL(k) const float s##k = __uint_as_float(__builtin_amdgcn_readlane(hvu, k));

// ---- 4 register rows against 4 broadcast scalars ----
#define DOT16(i,A,B,C,D) \
  a0=fmaf(wa_##i.x,A,a0); a0=fmaf(wa_##i.y,B,a0); a0=fmaf(wa_##i.z,C,a0); a0=fmaf(wa_##i.w,D,a0); \
  a1=fmaf(wb_##i.x,A,a1); a1=fmaf(wb_##i.y,B,a1); a1=fmaf(wb_##i.z,C,a1); a1=fmaf(wb_##i.w,D,a1); \
  a2=fmaf(wc_##i.x,A,a2); a2=fmaf(wc_##i.y,B,a2); a2=fmaf(wc_##i.z,C,a2); a2=fmaf(wc_##i.w,D,a2); \
  a3=fmaf(wd_##i.x,A,a3); a3=fmaf(wd_##i.y,B,a3); a3=fmaf(wd_##i.z,C,a3); a3=fmaf(wd_##i.w,D,a3);

// ---- LDS task row (contiguous [slot][52], b128 reads) against scalars ----
#define TQ4(k,A,B,C,D) { const float4 v_=tp4[k]; t0=fmaf(v_.x,A,t0); t0=fmaf(v_.y,B,t0); \
                         t1=fmaf(v_.z,C,t1); t1=fmaf(v_.w,D,t1); }
#define TASKDOT(slot,row,tb) { \
  const float4* tp4 = reinterpret_cast<const float4*>(wq + ((hf*NTASKS)+(slot))*52); \
  float t0=0.f, t1=0.f; \
  TQ4(0,s0,s1,s2,s3)      TQ4(1,s4,s5,s6,s7)      TQ4(2,s8,s9,s10,s11) \
  TQ4(3,s12,s13,s14,s15)  TQ4(4,s16,s17,s18,s19)  TQ4(5,s20,s21,s22,s23) \
  TQ4(6,s24,s25,s26,s27)  TQ4(7,s28,s29,s30,s31)  TQ4(8,s32,s33,s34,s35) \
  TQ4(9,s36,s37,s38,s39)  TQ4(10,s40,s41,s42,s43) TQ4(11,s44,s45,s46,s47) \
  { const float2 v2_ = reinterpret_cast<const float2*>(tp4)[24]; \
    t0=fmaf(v2_.x,s48,t0); t1=fmaf(v2_.y,s49,t1); } \
  pw[row] = fmaf((tb), xvs, t0+t1); }

__global__ __launch_bounds__(NT, 1)
void lstm_r8_kernel(const float* __restrict__ x_seq,
                    const float* __restrict__ Wih0,
                    const float* __restrict__ Whh0,
                    const float* __restrict__ bih0,
                    const float* __restrict__ bhh0,
                    const float* __restrict__ Wih1,
                    const float* __restrict__ Whh1,
                    const float* __restrict__ bih1,
                    const float* __restrict__ bhh1,
                    const float* __restrict__ Wlin,
                    const float* __restrict__ blin,
                    float* __restrict__ out)
{
    extern __shared__ float lds[];
    float* x_s  = lds;                  // [4096]
    float* wq   = lds + WQ_OFF;         // [2][176][52]
    float* part = lds + PART_OFF;       // [2buf][2hf][1204]
    float* red  = lds + RED_OFF;        // [128]

    const int tid  = threadIdx.x;
    const int lane = tid & 63;
    const int wid  = tid >> 6;
    const int hf   = wid & 1;
    const bool is_h1 = (wid < 6);

    // ---- prologue: x ----
    {
        const float4* src = reinterpret_cast<const float4*>(x_seq);
        float4*       dst = reinterpret_cast<float4*>(x_s);
        for (int i = tid; i < LL/4; i += NT) dst[i] = src[i];
    }
    // ---- wq: slots 0..31 = Whh0 rows 0..31 (h1); 32..175 = Whh1 rows 0..143 (h2) ----
    for (int idx = tid; idx < 2*NTASKS*50; idx += NT) {
        int h   = idx / (NTASKS*50);
        int rem = idx - h*(NTASKS*50);
        int s   = rem / 50;
        int c   = rem - s*50;
        float v = (s < 32) ? Whh0[s*HH + h*50 + c] : Whh1[(s-32)*HH + h*50 + c];
        wq[(h*NTASKS + s)*52 + c] = v;
    }

    // ---- register rows (4 rows x 50 cols, named) ----
    int j = 0, j2 = 0, r0;
    const float* M;
    if (is_h1) {
        j  = (wid >> 1)*64 + lane;           // 0..191
        r0 = 32 + 4*j;                       // 32..795
        M  = (r0 < 400) ? (Whh0 + r0*HH) : (Wih1 + (r0-400)*HH);
    } else {
        j2 = lane;                           // 0..63
        r0 = 944 + 4*j2;                     // 944..1196
        M  = Whh1 + (r0-800)*HH;
    }
    DECLROW(wa) DECLROW(wb) DECLROW(wc) DECLROW(wd)
    LOADROW(wa, M + 0*HH + hf*50)
    LOADROW(wb, M + 1*HH + hf*50)
    LOADROW(wc, M + 2*HH + hf*50)
    LOADROW(wd, M + 3*HH + hf*50)

    // bias (hf0) / wx (hf1, L0 rows only); h2 reg rows carry neither
    float bw0 = 0.f, bw1 = 0.f, bw2 = 0.f, bw3 = 0.f;
    if (is_h1) {
        const int ra = r0, rb = r0+1, rc = r0+2, rd = r0+3;
        if (hf == 0) {
            bw0 = (ra < 400) ? (bih0[ra] + bhh0[ra]) : (bih1[ra-400] + bhh1[ra-400]);
            bw1 = (rb < 400) ? (bih0[rb] + bhh0[rb]) : (bih1[rb-400] + bhh1[rb-400]);
            bw2 = (rc < 400) ? (bih0[rc] + bhh0[rc]) : (bih1[rc-400] + bhh1[rc-400]);
            bw3 = (rd < 400) ? (bih0[rd] + bhh0[rd]) : (bih1[rd-400] + bhh1[rd-400]);
        } else {
            bw0 = (ra < 400) ? Wih0[ra] : 0.f;
            bw1 = (rb < 400) ? Wih0[rb] : 0.f;
            bw2 = (rc < 400) ? Wih0[rc] : 0.f;
            bw3 = (rd < 400) ? Wih0[rd] : 0.f;
        }
    }

    // ---- task assignment ----
    int ntask = 0, slotA = 0, rowA = 0, slotB = 0, rowB = 0, slotC = 0, rowC = 0;
    float tbwA = 0.f;
    if (is_h1) {
        if (j < 32) { ntask = 1; slotA = j; rowA = j;
                      tbwA = (hf == 0) ? (bih0[j] + bhh0[j]) : Wih0[j]; }
    } else {
        ntask = (j2 < 16) ? 3 : 2;
        slotA = 32 + j2;   rowA = 800 + j2;
        slotB = 96 + j2;   rowB = 864 + j2;
        slotC = 160 + j2;  rowC = 928 + j2;
    }

    // epilogue weight (h2 waves hold final h2)
    float wl = 0.f;
    if (!is_h1 && lane < 50) wl = Wlin[hf*50 + lane];

    const int e = hf*50 + ((lane < 50) ? lane : 49);   // gating element (global h index)

    float h_lane = 0.f, c_lane = 0.f;
    __syncthreads();

    for (int t = 0; t <= LL; ++t) {
        const float xt  = x_s[(t < LL) ? t : (LL-1)];
        const float xvs = hf ? xt : 1.0f;
        float*       pw  = part + (t & 1)*2408 + hf*1204;
        const float* pr0 = part + (t & 1)*2408;
        const float* pr1 = pr0 + 1204;

        // ---- stage own-class h into SGPRs (intra-wave handoff; no LDS) ----
        const unsigned hvu = __float_as_uint(h_lane);
        RL(0) RL(1) RL(2) RL(3) RL(4) RL(5) RL(6) RL(7) RL(8) RL(9)
        RL(10) RL(11) RL(12) RL(13) RL(14) RL(15) RL(16) RL(17) RL(18) RL(19)
        RL(20) RL(21) RL(22) RL(23) RL(24) RL(25) RL(26) RL(27) RL(28) RL(29)
        RL(30) RL(31) RL(32) RL(33) RL(34) RL(35) RL(36) RL(37) RL(38) RL(39)
        RL(40) RL(41) RL(42) RL(43) RL(44) RL(45) RL(46) RL(47) RL(48) RL(49)

        // ---- register-row dots (4 rows) ----
        float a0 = 0.f, a1 = 0.f, a2 = 0.f, a3 = 0.f;
        DOT16(0, s0,s1,s2,s3)      DOT16(1, s4,s5,s6,s7)      DOT16(2, s8,s9,s10,s11)
        DOT16(3, s12,s13,s14,s15)  DOT16(4, s16,s17,s18,s19)  DOT16(5, s20,s21,s22,s23)
        DOT16(6, s24,s25,s26,s27)  DOT16(7, s28,s29,s30,s31)  DOT16(8, s32,s33,s34,s35)
        DOT16(9, s36,s37,s38,s39)  DOT16(10, s40,s41,s42,s43) DOT16(11, s44,s45,s46,s47)
        a0 = fmaf(wa_12.x, s48, a0); a0 = fmaf(wa_12.y, s49, a0);
        a1 = fmaf(wb_12.x, s48, a1); a1 = fmaf(wb_12.y, s49, a1);
        a2 = fmaf(wc_12.x, s48, a2); a2 = fmaf(wc_12.y, s49, a2);
        a3 = fmaf(wd_12.x, s48, a3); a3 = fmaf(wd_12.y, s49, a3);
        a0 = fmaf(bw0, xvs, a0);
        a1 = fmaf(bw1, xvs, a1);
        a2 = fmaf(bw2, xvs, a2);
        a3 = fmaf(bw3, xvs, a3);
        reinterpret_cast<float4*>(pw + r0)[0] = make_float4(a0, a1, a2, a3);

        // ---- LDS-streamed task rows ----
        if (ntask >= 1) { TASKDOT(slotA, rowA, tbwA) }
        if (ntask >= 2) { TASKDOT(slotB, rowB, 0.f) }
        if (ntask >= 3) { TASKDOT(slotC, rowC, 0.f) }

        __syncthreads();   // the ONLY barrier per step

        // ---- lane-parallel redundant gating ----
        if (is_h1) {
            float G0 = pr0[e]       + pr1[e];
            float G1 = pr0[e + 100] + pr1[e + 100];
            float G2 = pr0[e + 200] + pr1[e + 200];
            float G3 = pr0[e + 300] + pr1[e + 300];
            c_lane = sigmoidf_(G1)*c_lane + sigmoidf_(G0)*tanhf_(G2);
            h_lane = sigmoidf_(G3)*tanhf_(c_lane);
        } else if (t >= 1) {
            float G0 = (pr0[400+e]  + pr1[400+e])  + (pr0[800+e]  + pr1[800+e]);
            float G1 = (pr0[500+e]  + pr1[500+e])  + (pr0[900+e]  + pr1[900+e]);
            float G2 = (pr0[600+e]  + pr1[600+e])  + (pr0[1000+e] + pr1[1000+e]);
            float G3 = (pr0[700+e]  + pr1[700+e])  + (pr0[1100+e] + pr1[1100+e]);
            c_lane = sigmoidf_(G1)*c_lane + sigmoidf_(G0)*tanhf_(G2);
            h_lane = sigmoidf_(G3)*tanhf_(c_lane);
        }
        // no second barrier: next iter writes the other part buffer; h handoff is in-register
    }

    // ---- final projection: h2(LL-1) in lanes<50 of waves 6,7 ----
    if (!is_h1 && lane < 50) red[hf*50 + lane] = wl * h_lane;
    __syncthreads();
    if (tid == 0) {
        float s = blin[0];
        for (int k = 0; k < HH; ++k) s += red[k];
        out[0] = s;
    }
}

extern "C" void kernel_launch(void* const* d_in, const int* in_sizes, int n_in,
                              void* d_out, int out_size, void* d_ws, size_t ws_size,
                              hipStream_t stream) {
    (void)in_sizes; (void)n_in; (void)out_size; (void)d_ws; (void)ws_size;

    const float* x_seq = (const float*)d_in[0];
    const float* Wih0  = (const float*)d_in[1];
    const float* Whh0  = (const float*)d_in[2];
    const float* bih0  = (const float*)d_in[3];
    const float* bhh0  = (const float*)d_in[4];
    const float* Wih1  = (const float*)d_in[5];
    const float* Whh1  = (const float*)d_in[6];
    const float* bih1  = (const float*)d_in[7];
    const float* bhh1  = (const float*)d_in[8];
    const float* Wlin  = (const float*)d_in[9];
    const float* blin  = (const float*)d_in[10];
    float* out = (float*)d_out;

    static bool attr_set = false;
    if (!attr_set) {
        hipFuncSetAttribute((const void*)lstm_r8_kernel,
                            hipFuncAttributeMaxDynamicSharedMemorySize,
                            LDS_FLOATS * (int)sizeof(float));
        attr_set = true;
    }

    hipLaunchKernelGGL(lstm_r8_kernel, dim3(1), dim3(NT),
                       LDS_FLOATS * sizeof(float), stream,
                       x_seq, Wih0, Whh0, bih0, bhh0,
                       Wih1, Whh1, bih1, bhh1, Wlin, blin, out);
}

// Round 9
// 6507.157 us; speedup vs baseline: 1.4472x; 1.2999x over previous
//
#include <hip/hip_runtime.h>

#define HH   100
#define LL   4096
#define NT   512
#define NLDSROW 176          // W_all rows 0..175 (= Whh0 gates 0..175) streamed from LDS
#define RB0  176             // first register-resident row
// Row space r in [0,1200): [0,400) Whh0 (src h1), [400,800) Wih1 (src h1), [800,1200) Whh1 (src h2).
// Thread: qid=tid>>1 (4 rows RB0+4q..+3), half=tid&1 (cols 50h..50h+49). 200 weight floats as 100 named v2f.
// Dots accumulate in 2-wide vectors -> v_pk_fma_f32 (packed fp32 FMA, gfx950).

// LDS floats: x[4096] wq[2][176][52] h1[104] h2[104] part[2048] q[352]
#define WQ_OFF   4096
#define H1_OFF   (WQ_OFF + 2*NLDSROW*52)     // 22400
#define H2_OFF   (H1_OFF + 104)              // 22504
#define PART_OFF (H2_OFF + 104)              // 22608
#define Q_OFF    (PART_OFF + 2048)           // 24656
#define LDS_FLOATS (Q_OFF + 352)             // 25008 floats = 100 KB

typedef float v2f __attribute__((ext_vector_type(2)));
__device__ __forceinline__ v2f fma2(v2f a, v2f b, v2f c) { return __builtin_elementwise_fma(a, b, c); }
__device__ __forceinline__ v2f v2c(float2 f) { v2f r; r.x = f.x; r.y = f.y; return r; }

__device__ __forceinline__ float sigmoidf_(float x) {
    return 1.0f / (1.0f + __expf(-x));
}
__device__ __forceinline__ float tanhf_(float x) {
    return 1.0f - 2.0f / (__expf(2.0f * x) + 1.0f);
}

// ---- named register rows: 25 v2f = 50 floats (no alloca) ----
#define DECLROW(n) v2f n##_0,n##_1,n##_2,n##_3,n##_4,n##_5,n##_6,n##_7,n##_8,n##_9,n##_10,n##_11, \
                       n##_12,n##_13,n##_14,n##_15,n##_16,n##_17,n##_18,n##_19,n##_20,n##_21,n##_22,n##_23,n##_24;
#define LOADROW(n, P) { const float2* q2_ = reinterpret_cast<const float2*>(P); \
  n##_0=v2c(q2_[0]);   n##_1=v2c(q2_[1]);   n##_2=v2c(q2_[2]);   n##_3=v2c(q2_[3]);   n##_4=v2c(q2_[4]); \
  n##_5=v2c(q2_[5]);   n##_6=v2c(q2_[6]);   n##_7=v2c(q2_[7]);   n##_8=v2c(q2_[8]);   n##_9=v2c(q2_[9]); \
  n##_10=v2c(q2_[10]); n##_11=v2c(q2_[11]); n##_12=v2c(q2_[12]); n##_13=v2c(q2_[13]); n##_14=v2c(q2_[14]); \
  n##_15=v2c(q2_[15]); n##_16=v2c(q2_[16]); n##_17=v2c(q2_[17]); n##_18=v2c(q2_[18]); n##_19=v2c(q2_[19]); \
  n##_20=v2c(q2_[20]); n##_21=v2c(q2_[21]); n##_22=v2c(q2_[22]); n##_23=v2c(q2_[23]); n##_24=v2c(q2_[24]); }

// ---- dot step j (h float4 -> two v2f), 4 rows ----
#define STEP(j,p,q) { float4 hv = hb4[j]; v2f hl, hh; hl.x=hv.x; hl.y=hv.y; hh.x=hv.z; hh.y=hv.w; \
  a0=fma2(wa_##p,hl,a0); a0=fma2(wa_##q,hh,a0); \
  a1=fma2(wb_##p,hl,a1); a1=fma2(wb_##q,hh,a1); \
  a2=fma2(wc_##p,hl,a2); a2=fma2(wc_##q,hh,a2); \
  a3=fma2(wd_##p,hl,a3); a3=fma2(wd_##q,hh,a3); }

// ---- task step (contiguous wq row, b128 reads) ----
#define TSK(j,p,q) { float4 wv = tp4[j]; float4 hv = hb4t[j]; v2f wl_,wh_,hl_,hh_; \
  wl_.x=wv.x; wl_.y=wv.y; wh_.x=wv.z; wh_.y=wv.w; hl_.x=hv.x; hl_.y=hv.y; hh_.x=hv.z; hh_.y=hv.w; \
  tq=fma2(wl_,hl_,tq); tq=fma2(wh_,hh_,tq); }

__global__ __attribute__((amdgpu_flat_work_group_size(NT, NT)))
           __attribute__((amdgpu_waves_per_eu(2, 2)))
void lstm_pk_kernel(const float* __restrict__ x_seq,
                    const float* __restrict__ Wih0,
                    const float* __restrict__ Whh0,
                    const float* __restrict__ bih0,
                    const float* __restrict__ bhh0,
                    const float* __restrict__ Wih1,
                    const float* __restrict__ Whh1,
                    const float* __restrict__ bih1,
                    const float* __restrict__ bhh1,
                    const float* __restrict__ Wlin,
                    const float* __restrict__ blin,
                    float* __restrict__ out)
{
    extern __shared__ float lds[];
    float* x_s    = lds;                 // [4096]
    float* wq     = lds + WQ_OFF;        // [2][176][52] contiguous rows
    float* h1_s   = lds + H1_OFF;        // [104] padded: h[e] at e + 2*(e>=50)
    float* h2_s   = lds + H2_OFF;        // [104]
    float* part_s = lds + PART_OFF;      // [2048]: slot = ((row-176)>>2) + ((row-176)&3)*256 + half*1024
    float* q_s    = lds + Q_OFF;         // [352]: row + 176*half

    const int tid  = threadIdx.x;
    const int half = tid & 1;
    const int qid  = tid >> 1;           // 0..255
    const int rowbase = RB0 + 4*qid;     // 176..1196, region-aligned

    // ---- prologue: x ----
    {
        const float4* src = reinterpret_cast<const float4*>(x_seq);
        float4*       dst = reinterpret_cast<float4*>(x_s);
        for (int i = tid; i < LL/4; i += NT) dst[i] = src[i];
    }
    // ---- wq: contiguous rows [half][row][52] of Whh0 rows 0..175 ----
    for (int idx = tid; idx < 2*NLDSROW*50; idx += NT) {
        int hf  = idx / (NLDSROW*50);
        int rem = idx - hf*(NLDSROW*50);
        int row = rem / 50;
        int c   = rem - row*50;
        wq[(hf*NLDSROW + row)*52 + c] = Whh0[row*HH + hf*50 + c];
    }
    if (tid < 104) { h1_s[tid] = 0.0f; h2_s[tid] = 0.0f; }

    // ---- per-thread register weights: 4 rows x 50 cols as 100 named v2f ----
    const float* M; int r0;
    if (rowbase < 400)      { M = Whh0; r0 = rowbase; }
    else if (rowbase < 800) { M = Wih1; r0 = rowbase - 400; }
    else                    { M = Whh1; r0 = rowbase - 800; }

    DECLROW(wa) DECLROW(wb) DECLROW(wc) DECLROW(wd)
    LOADROW(wa, M + (r0+0)*HH + half*50)
    LOADROW(wb, M + (r0+1)*HH + half*50)
    LOADROW(wc, M + (r0+2)*HH + half*50)
    LOADROW(wd, M + (r0+3)*HH + half*50)

    // bias / wx per row (meaning depends on half; applied via xvs = half? xt : 1)
    float bw0, bw1, bw2, bw3;
    {
        const int ra = rowbase, rb = rowbase+1, rc = rowbase+2, rd = rowbase+3;
        if (half == 0) {
            bw0 = (ra < 400) ? (bih0[ra] + bhh0[ra]) : (ra < 800) ? (bih1[ra-400] + bhh1[ra-400]) : 0.0f;
            bw1 = (rb < 400) ? (bih0[rb] + bhh0[rb]) : (rb < 800) ? (bih1[rb-400] + bhh1[rb-400]) : 0.0f;
            bw2 = (rc < 400) ? (bih0[rc] + bhh0[rc]) : (rc < 800) ? (bih1[rc-400] + bhh1[rc-400]) : 0.0f;
            bw3 = (rd < 400) ? (bih0[rd] + bhh0[rd]) : (rd < 800) ? (bih1[rd-400] + bhh1[rd-400]) : 0.0f;
        } else {
            bw0 = (ra < 400) ? Wih0[ra] : 0.0f;
            bw1 = (rb < 400) ? Wih0[rb] : 0.0f;
            bw2 = (rc < 400) ? Wih0[rc] : 0.0f;
            bw3 = (rd < 400) ? Wih0[rd] : 0.0f;
        }
    }

    // LDS-task constants (threads 0..351: row qid<176, this thread's half)
    float lb = 0.0f;
    if (tid < 2*NLDSROW) {
        lb = half ? Wih0[qid] : (bih0[qid] + bhh0[qid]);
    }
    const float4* tp4  = reinterpret_cast<const float4*>(wq + (half*NLDSROW + qid)*52);
    const float4* hb4t = reinterpret_cast<const float4*>(h1_s + half*52);   // tasks are h1-source

    // h source for register dots (wave-cheap LDS broadcast)
    const float4* hb4 = reinterpret_cast<const float4*>(
        ((rowbase < 800) ? h1_s : h2_s) + half*52);

    const float wl = (tid < HH) ? Wlin[tid] : 0.0f;
    const int slotbase = qid + half*1024;
    float c0 = 0.0f, c1 = 0.0f;

    __syncthreads();

    for (int t = 0; t <= LL; ++t) {
        const float xt  = x_s[(t < LL) ? t : (LL-1)];
        const float xvs = half ? xt : 1.0f;

        // === dot phase: 4 register rows, packed-FMA accumulation ===
        {
            v2f a0 = {0.f,0.f}, a1 = {0.f,0.f}, a2 = {0.f,0.f}, a3 = {0.f,0.f};
            STEP(0,0,1)   STEP(1,2,3)   STEP(2,4,5)   STEP(3,6,7)
            STEP(4,8,9)   STEP(5,10,11) STEP(6,12,13) STEP(7,14,15)
            STEP(8,16,17) STEP(9,18,19) STEP(10,20,21) STEP(11,22,23)
            {   // tail pair (cols 48,49); hb4[12].xy are h48,h49 (pad .zw)
                float4 hv = hb4[12]; v2f hl; hl.x = hv.x; hl.y = hv.y;
                a0 = fma2(wa_24, hl, a0);
                a1 = fma2(wb_24, hl, a1);
                a2 = fma2(wc_24, hl, a2);
                a3 = fma2(wd_24, hl, a3);
            }
            part_s[slotbase + 0*256] = fmaf(bw0, xvs, a0.x + a0.y);
            part_s[slotbase + 1*256] = fmaf(bw1, xvs, a1.x + a1.y);
            part_s[slotbase + 2*256] = fmaf(bw2, xvs, a2.x + a2.y);
            part_s[slotbase + 3*256] = fmaf(bw3, xvs, a3.x + a3.y);
        }
        // === LDS-streamed rows 0..175 (h1-source), packed accumulation ===
        if (tid < 2*NLDSROW) {
            v2f tq = {0.f,0.f};
            TSK(0,,) TSK(1,,) TSK(2,,) TSK(3,,) TSK(4,,) TSK(5,,)
            TSK(6,,) TSK(7,,) TSK(8,,) TSK(9,,) TSK(10,,) TSK(11,,)
            {   // tail pair
                float4 wv = tp4[12]; float4 hv = hb4t[12];
                v2f wl_, hl_; wl_.x = wv.x; wl_.y = wv.y; hl_.x = hv.x; hl_.y = hv.y;
                tq = fma2(wl_, hl_, tq);
            }
            q_s[qid + half*NLDSROW] = fmaf(lb, xvs, tq.x + tq.y);
        }
        __syncthreads();

        // === gating phase ===
        if (tid < HH) {                          // L0 gating -> h1(t)
            const int j = tid;
            float g[4];
            #pragma unroll
            for (int k = 0; k < 4; ++k) {
                int r = j + k*100;
                if (r < NLDSROW) {
                    g[k] = q_s[r] + q_s[r + NLDSROW];
                } else {
                    int rr = r - RB0;
                    int b  = (rr >> 2) + ((rr & 3) << 8);
                    g[k] = part_s[b] + part_s[b + 1024];
                }
            }
            if (t < LL) {
                c0 = sigmoidf_(g[1])*c0 + sigmoidf_(g[0])*tanhf_(g[2]);
                h1_s[j + 2*(j >= 50)] = sigmoidf_(g[3])*tanhf_(c0);
            }
        } else if (tid >= 128 && tid < 128 + HH) {   // L1 gating -> h2(t-1)
            if (t >= 1) {
                const int j = tid - 128;
                float v[4];
                #pragma unroll
                for (int k = 0; k < 4; ++k) {
                    int g = j + k*100;
                    int rr1 = (400 + g) - RB0;
                    int b1i = (rr1 >> 2) + ((rr1 & 3) << 8);
                    int rr2 = (800 + g) - RB0;
                    int b2i = (rr2 >> 2) + ((rr2 & 3) << 8);
                    v[k] = (part_s[b1i] + part_s[b1i + 1024])
                         + (part_s[b2i] + part_s[b2i + 1024]);
                }
                c1 = sigmoidf_(v[1])*c1 + sigmoidf_(v[0])*tanhf_(v[2]);
                h2_s[j + 2*(j >= 50)] = sigmoidf_(v[3])*tanhf_(c1);
            }
        }
        __syncthreads();
    }

    // ---- final projection: out = h2(L-1) . Wlin + blin ----
    if (tid < HH) part_s[tid] = wl * h2_s[tid + 2*(tid >= 50)];
    __syncthreads();
    if (tid == 0) {
        float s = 0.0f;
        for (int k = 0; k < HH; ++k) s += part_s[k];
        out[0] = s + blin[0];
    }
}

extern "C" void kernel_launch(void* const* d_in, const int* in_sizes, int n_in,
                              void* d_out, int out_size, void* d_ws, size_t ws_size,
                              hipStream_t stream) {
    (void)in_sizes; (void)n_in; (void)out_size; (void)d_ws; (void)ws_size;

    const float* x_seq = (const float*)d_in[0];
    const float* Wih0  = (const float*)d_in[1];
    const float* Whh0  = (const float*)d_in[2];
    const float* bih0  = (const float*)d_in[3];
    const float* bhh0  = (const float*)d_in[4];
    const float* Wih1  = (const float*)d_in[5];
    const float* Whh1  = (const float*)d_in[6];
    const float* bih1  = (const float*)d_in[7];
    const float* bhh1  = (const float*)d_in[8];
    const float* Wlin  = (const float*)d_in[9];
    const float* blin  = (const float*)d_in[10];
    float* out = (float*)d_out;

    static bool attr_set = false;
    if (!attr_set) {
        hipFuncSetAttribute((const void*)lstm_pk_kernel,
                            hipFuncAttributeMaxDynamicSharedMemorySize,
                            LDS_FLOATS * (int)sizeof(float));
        attr_set = true;
    }

    hipLaunchKernelGGL(lstm_pk_kernel, dim3(1), dim3(NT),
                       LDS_FLOATS * sizeof(float), stream,
                       x_seq, Wih0, Whh0, bih0, bhh0,
                       Wih1, Whh1, bih1, bhh1, Wlin, blin, out);
}

// Round 10
// 6499.354 us; speedup vs baseline: 1.4489x; 1.0012x over previous
//
#include <hip/hip_runtime.h>

#define HH   100
#define LL   4096
#define NT   512
#define NLDSROW 176          // W_all rows 0..175 (= Whh0 gates 0..175) streamed from LDS
#define RB0  176             // first register-resident row
// Row space r in [0,1200): [0,400) Whh0 (src h1), [400,800) Wih1 (src h1), [800,1200) Whh1 (src h2).
// Thread: qid=tid>>1 (4 rows RB0+4q..+3), half=tid&1 (cols 50h..50h+49). 200 weight floats as 100 named v2f.
// Dots accumulate in 2-wide vectors -> v_pk_fma_f32. amdgpu_num_vgpr(256) requests full arch-VGPR file
// (2 waves/EU x 256 = 512 regs/SIMD) so weights avoid the AGPR-move tax.

// LDS floats: x[4096] wq[2][176][52] h1[104] h2[104] part[2048] q[352]
#define WQ_OFF   4096
#define H1_OFF   (WQ_OFF + 2*NLDSROW*52)     // 22400
#define H2_OFF   (H1_OFF + 104)              // 22504
#define PART_OFF (H2_OFF + 104)              // 22608
#define Q_OFF    (PART_OFF + 2048)           // 24656
#define LDS_FLOATS (Q_OFF + 352)             // 25008 floats = 100 KB

typedef float v2f __attribute__((ext_vector_type(2)));
__device__ __forceinline__ v2f fma2(v2f a, v2f b, v2f c) { return __builtin_elementwise_fma(a, b, c); }
__device__ __forceinline__ v2f v2c(float2 f) { v2f r; r.x = f.x; r.y = f.y; return r; }

__device__ __forceinline__ float sigmoidf_(float x) {
    return 1.0f / (1.0f + __expf(-x));
}
__device__ __forceinline__ float tanhf_(float x) {
    return 1.0f - 2.0f / (__expf(2.0f * x) + 1.0f);
}

// ---- named register rows: 25 v2f = 50 floats (no alloca) ----
#define DECLROW(n) v2f n##_0,n##_1,n##_2,n##_3,n##_4,n##_5,n##_6,n##_7,n##_8,n##_9,n##_10,n##_11, \
                       n##_12,n##_13,n##_14,n##_15,n##_16,n##_17,n##_18,n##_19,n##_20,n##_21,n##_22,n##_23,n##_24;
#define LOADROW(n, P) { const float2* q2_ = reinterpret_cast<const float2*>(P); \
  n##_0=v2c(q2_[0]);   n##_1=v2c(q2_[1]);   n##_2=v2c(q2_[2]);   n##_3=v2c(q2_[3]);   n##_4=v2c(q2_[4]); \
  n##_5=v2c(q2_[5]);   n##_6=v2c(q2_[6]);   n##_7=v2c(q2_[7]);   n##_8=v2c(q2_[8]);   n##_9=v2c(q2_[9]); \
  n##_10=v2c(q2_[10]); n##_11=v2c(q2_[11]); n##_12=v2c(q2_[12]); n##_13=v2c(q2_[13]); n##_14=v2c(q2_[14]); \
  n##_15=v2c(q2_[15]); n##_16=v2c(q2_[16]); n##_17=v2c(q2_[17]); n##_18=v2c(q2_[18]); n##_19=v2c(q2_[19]); \
  n##_20=v2c(q2_[20]); n##_21=v2c(q2_[21]); n##_22=v2c(q2_[22]); n##_23=v2c(q2_[23]); n##_24=v2c(q2_[24]); }

// ---- dot step j (h float4 -> two v2f), 4 rows ----
#define STEP(j,p,q) { float4 hv = hb4[j]; v2f hl, hh; hl.x=hv.x; hl.y=hv.y; hh.x=hv.z; hh.y=hv.w; \
  a0=fma2(wa_##p,hl,a0); a0=fma2(wa_##q,hh,a0); \
  a1=fma2(wb_##p,hl,a1); a1=fma2(wb_##q,hh,a1); \
  a2=fma2(wc_##p,hl,a2); a2=fma2(wc_##q,hh,a2); \
  a3=fma2(wd_##p,hl,a3); a3=fma2(wd_##q,hh,a3); }

// ---- task step (contiguous wq row, b128 reads) ----
#define TSK(j) { float4 wv = tp4[j]; float4 hv = hb4t[j]; v2f wl_,wh_,hl_,hh_; \
  wl_.x=wv.x; wl_.y=wv.y; wh_.x=wv.z; wh_.y=wv.w; hl_.x=hv.x; hl_.y=hv.y; hh_.x=hv.z; hh_.y=hv.w; \
  tq=fma2(wl_,hl_,tq); tq=fma2(wh_,hh_,tq); }

__global__ __attribute__((amdgpu_flat_work_group_size(NT, NT)))
           __attribute__((amdgpu_waves_per_eu(2, 2)))
           __attribute__((amdgpu_num_vgpr(256)))
void lstm_v256_kernel(const float* __restrict__ x_seq,
                      const float* __restrict__ Wih0,
                      const float* __restrict__ Whh0,
                      const float* __restrict__ bih0,
                      const float* __restrict__ bhh0,
                      const float* __restrict__ Wih1,
                      const float* __restrict__ Whh1,
                      const float* __restrict__ bih1,
                      const float* __restrict__ bhh1,
                      const float* __restrict__ Wlin,
                      const float* __restrict__ blin,
                      float* __restrict__ out)
{
    extern __shared__ float lds[];
    float* x_s    = lds;                 // [4096]
    float* wq     = lds + WQ_OFF;        // [2][176][52] contiguous rows
    float* h1_s   = lds + H1_OFF;        // [104] padded: h[e] at e + 2*(e>=50)
    float* h2_s   = lds + H2_OFF;        // [104]
    float* part_s = lds + PART_OFF;      // [2048]: slot = ((row-176)>>2) + ((row-176)&3)*256 + half*1024
    float* q_s    = lds + Q_OFF;         // [352]: row + 176*half

    const int tid  = threadIdx.x;
    const int half = tid & 1;
    const int qid  = tid >> 1;           // 0..255
    const int rowbase = RB0 + 4*qid;     // 176..1196, region-aligned

    // ---- prologue: x ----
    {
        const float4* src = reinterpret_cast<const float4*>(x_seq);
        float4*       dst = reinterpret_cast<float4*>(x_s);
        for (int i = tid; i < LL/4; i += NT) dst[i] = src[i];
    }
    // ---- wq: contiguous rows [half][row][52] of Whh0 rows 0..175 ----
    for (int idx = tid; idx < 2*NLDSROW*50; idx += NT) {
        int hf  = idx / (NLDSROW*50);
        int rem = idx - hf*(NLDSROW*50);
        int row = rem / 50;
        int c   = rem - row*50;
        wq[(hf*NLDSROW + row)*52 + c] = Whh0[row*HH + hf*50 + c];
    }
    if (tid < 104) { h1_s[tid] = 0.0f; h2_s[tid] = 0.0f; }

    // ---- per-thread register weights: 4 rows x 50 cols as 100 named v2f ----
    const float* M; int r0;
    if (rowbase < 400)      { M = Whh0; r0 = rowbase; }
    else if (rowbase < 800) { M = Wih1; r0 = rowbase - 400; }
    else                    { M = Whh1; r0 = rowbase - 800; }

    DECLROW(wa) DECLROW(wb) DECLROW(wc) DECLROW(wd)
    LOADROW(wa, M + (r0+0)*HH + half*50)
    LOADROW(wb, M + (r0+1)*HH + half*50)
    LOADROW(wc, M + (r0+2)*HH + half*50)
    LOADROW(wd, M + (r0+3)*HH + half*50)

    // bias / wx per row (meaning depends on half; applied via xvs = half? xt : 1)
    float bw0, bw1, bw2, bw3;
    {
        const int ra = rowbase, rb = rowbase+1, rc = rowbase+2, rd = rowbase+3;
        if (half == 0) {
            bw0 = (ra < 400) ? (bih0[ra] + bhh0[ra]) : (ra < 800) ? (bih1[ra-400] + bhh1[ra-400]) : 0.0f;
            bw1 = (rb < 400) ? (bih0[rb] + bhh0[rb]) : (rb < 800) ? (bih1[rb-400] + bhh1[rb-400]) : 0.0f;
            bw2 = (rc < 400) ? (bih0[rc] + bhh0[rc]) : (rc < 800) ? (bih1[rc-400] + bhh1[rc-400]) : 0.0f;
            bw3 = (rd < 400) ? (bih0[rd] + bhh0[rd]) : (rd < 800) ? (bih1[rd-400] + bhh1[rd-400]) : 0.0f;
        } else {
            bw0 = (ra < 400) ? Wih0[ra] : 0.0f;
            bw1 = (rb < 400) ? Wih0[rb] : 0.0f;
            bw2 = (rc < 400) ? Wih0[rc] : 0.0f;
            bw3 = (rd < 400) ? Wih0[rd] : 0.0f;
        }
    }

    // LDS-task constants (threads 0..351: row qid<176, this thread's half)
    float lb = 0.0f;
    if (tid < 2*NLDSROW) {
        lb = half ? Wih0[qid] : (bih0[qid] + bhh0[qid]);
    }
    const float4* tp4  = reinterpret_cast<const float4*>(wq + (half*NLDSROW + qid)*52);
    const float4* hb4t = reinterpret_cast<const float4*>(h1_s + half*52);   // tasks are h1-source

    // h source for register dots (wave-cheap LDS broadcast)
    const float4* hb4 = reinterpret_cast<const float4*>(
        ((rowbase < 800) ? h1_s : h2_s) + half*52);

    const float wl = (tid < HH) ? Wlin[tid] : 0.0f;
    const int slotbase = qid + half*1024;
    float c0 = 0.0f, c1 = 0.0f;

    __syncthreads();

    for (int t = 0; t <= LL; ++t) {
        const float xt  = x_s[(t < LL) ? t : (LL-1)];
        const float xvs = half ? xt : 1.0f;

        // === dot phase: 4 register rows, packed-FMA accumulation ===
        {
            v2f a0 = {0.f,0.f}, a1 = {0.f,0.f}, a2 = {0.f,0.f}, a3 = {0.f,0.f};
            STEP(0,0,1)   STEP(1,2,3)   STEP(2,4,5)   STEP(3,6,7)
            STEP(4,8,9)   STEP(5,10,11) STEP(6,12,13) STEP(7,14,15)
            STEP(8,16,17) STEP(9,18,19) STEP(10,20,21) STEP(11,22,23)
            {   // tail pair (cols 48,49); hb4[12].xy are h48,h49 (pad .zw)
                float4 hv = hb4[12]; v2f hl; hl.x = hv.x; hl.y = hv.y;
                a0 = fma2(wa_24, hl, a0);
                a1 = fma2(wb_24, hl, a1);
                a2 = fma2(wc_24, hl, a2);
                a3 = fma2(wd_24, hl, a3);
            }
            part_s[slotbase + 0*256] = fmaf(bw0, xvs, a0.x + a0.y);
            part_s[slotbase + 1*256] = fmaf(bw1, xvs, a1.x + a1.y);
            part_s[slotbase + 2*256] = fmaf(bw2, xvs, a2.x + a2.y);
            part_s[slotbase + 3*256] = fmaf(bw3, xvs, a3.x + a3.y);
        }
        // === LDS-streamed rows 0..175 (h1-source), packed accumulation ===
        if (tid < 2*NLDSROW) {
            v2f tq = {0.f,0.f};
            TSK(0) TSK(1) TSK(2) TSK(3) TSK(4) TSK(5)
            TSK(6) TSK(7) TSK(8) TSK(9) TSK(10) TSK(11)
            {   // tail pair
                float4 wv = tp4[12]; float4 hv = hb4t[12];
                v2f wl_, hl_; wl_.x = wv.x; wl_.y = wv.y; hl_.x = hv.x; hl_.y = hv.y;
                tq = fma2(wl_, hl_, tq);
            }
            q_s[qid + half*NLDSROW] = fmaf(lb, xvs, tq.x + tq.y);
        }
        __syncthreads();

        // === gating phase ===
        if (tid < HH) {                          // L0 gating -> h1(t)
            const int j = tid;
            float g[4];
            #pragma unroll
            for (int k = 0; k < 4; ++k) {
                int r = j + k*100;
                if (r < NLDSROW) {
                    g[k] = q_s[r] + q_s[r + NLDSROW];
                } else {
                    int rr = r - RB0;
                    int b  = (rr >> 2) + ((rr & 3) << 8);
                    g[k] = part_s[b] + part_s[b + 1024];
                }
            }
            if (t < LL) {
                c0 = sigmoidf_(g[1])*c0 + sigmoidf_(g[0])*tanhf_(g[2]);
                h1_s[j + 2*(j >= 50)] = sigmoidf_(g[3])*tanhf_(c0);
            }
        } else if (tid >= 128 && tid < 128 + HH) {   // L1 gating -> h2(t-1)
            if (t >= 1) {
                const int j = tid - 128;
                float v[4];
                #pragma unroll
                for (int k = 0; k < 4; ++k) {
                    int g = j + k*100;
                    int rr1 = (400 + g) - RB0;
                    int b1i = (rr1 >> 2) + ((rr1 & 3) << 8);
                    int rr2 = (800 + g) - RB0;
                    int b2i = (rr2 >> 2) + ((rr2 & 3) << 8);
                    v[k] = (part_s[b1i] + part_s[b1i + 1024])
                         + (part_s[b2i] + part_s[b2i + 1024]);
                }
                c1 = sigmoidf_(v[1])*c1 + sigmoidf_(v[0])*tanhf_(v[2]);
                h2_s[j + 2*(j >= 50)] = sigmoidf_(v[3])*tanhf_(c1);
            }
        }
        __syncthreads();
    }

    // ---- final projection: out = h2(L-1) . Wlin + blin ----
    if (tid < HH) part_s[tid] = wl * h2_s[tid + 2*(tid >= 50)];
    __syncthreads();
    if (tid == 0) {
        float s = 0.0f;
        for (int k = 0; k < HH; ++k) s += part_s[k];
        out[0] = s + blin[0];
    }
}

extern "C" void kernel_launch(void* const* d_in, const int* in_sizes, int n_in,
                              void* d_out, int out_size, void* d_ws, size_t ws_size,
                              hipStream_t stream) {
    (void)in_sizes; (void)n_in; (void)out_size; (void)d_ws; (void)ws_size;

    const float* x_seq = (const float*)d_in[0];
    const float* Wih0  = (const float*)d_in[1];
    const float* Whh0  = (const float*)d_in[2];
    const float* bih0  = (const float*)d_in[3];
    const float* bhh0  = (const float*)d_in[4];
    const float* Wih1  = (const float*)d_in[5];
    const float* Whh1  = (const float*)d_in[6];
    const float* bih1  = (const float*)d_in[7];
    const float* bhh1  = (const float*)d_in[8];
    const float* Wlin  = (const float*)d_in[9];
    const float* blin  = (const float*)d_in[10];
    float* out = (float*)d_out;

    static bool attr_set = false;
    if (!attr_set) {
        hipFuncSetAttribute((const void*)lstm_v256_kernel,
                            hipFuncAttributeMaxDynamicSharedMemorySize,
                            LDS_FLOATS * (int)sizeof(float));
        attr_set = true;
    }

    hipLaunchKernelGGL(lstm_v256_kernel, dim3(1), dim3(NT),
                       LDS_FLOATS * sizeof(float), stream,
                       x_seq, Wih0, Whh0, bih0, bhh0,
                       Wih1, Whh1, bih1, bhh1, Wlin, blin, out);
}